// Round 1
// baseline (128.292 us; speedup 1.0000x reference)
//
#include <hip/hip_runtime.h>

// Problem: B=512 batch rows, T=128 time slabs, C=16 channels, fp32.
// out = E_xx - 2*E_xy where E_xx = weighted mean of off-diag RBF-gram entries
// per unique time slab t (w=1 for t in {0,127}, w=2 otherwise; 254 total slab
// instances), E_xy = weighted mean of all Kxy entries.
// exp(-d/2) = exp2((dot - 0.5*(na+nb)) * log2(e))  -> native v_exp_f32.

#define BATCH 512
#define TDIM  128
#define CDIM  16
#define LOG2E 1.4426950408889634f

static __device__ __forceinline__ float norm16(float4 a0, float4 a1, float4 a2, float4 a3) {
    float s0 = fmaf(a0.x, a0.x, fmaf(a1.x, a1.x, fmaf(a2.x, a2.x, a3.x * a3.x)));
    float s1 = fmaf(a0.y, a0.y, fmaf(a1.y, a1.y, fmaf(a2.y, a2.y, a3.y * a3.y)));
    float s2 = fmaf(a0.z, a0.z, fmaf(a1.z, a1.z, fmaf(a2.z, a2.z, a3.z * a3.z)));
    float s3 = fmaf(a0.w, a0.w, fmaf(a1.w, a1.w, fmaf(a2.w, a2.w, a3.w * a3.w)));
    return (s0 + s1) + (s2 + s3);
}

static __device__ __forceinline__ float dot16(float4 a0, float4 a1, float4 a2, float4 a3,
                                              float4 b0, float4 b1, float4 b2, float4 b3) {
    // 4 independent FMA chains for ILP
    float s0 = fmaf(a0.x, b0.x, fmaf(a1.x, b1.x, fmaf(a2.x, b2.x, a3.x * b3.x)));
    float s1 = fmaf(a0.y, b0.y, fmaf(a1.y, b1.y, fmaf(a2.y, b2.y, a3.y * b3.y)));
    float s2 = fmaf(a0.z, b0.z, fmaf(a1.z, b1.z, fmaf(a2.z, b2.z, a3.z * b3.z)));
    float s3 = fmaf(a0.w, b0.w, fmaf(a1.w, b1.w, fmaf(a2.w, b2.w, a3.w * b3.w)));
    return (s0 + s1) + (s2 + s3);
}

// grid = 512 blocks: bid>>2 = t (0..127), bid&3 = i-quarter.
// 256 threads: thread owns i = q*128 + (tid&127); jh = tid>>7 splits j-range.
// LDS stages j-rows of x and y in two chunks of 256 rows (34 KB total).
__global__ __launch_bounds__(256) void gram_kernel(const float* __restrict__ x,
                                                   const float* __restrict__ y,
                                                   float* __restrict__ part) {
    __shared__ float4 sx4[256 * 4];
    __shared__ float4 sy4[256 * 4];
    __shared__ float  snx[256];
    __shared__ float  sny[256];
    __shared__ float  red[8];

    const int bid = blockIdx.x;
    const int t   = bid >> 2;
    const int q   = bid & 3;
    const int tid = threadIdx.x;
    const int i   = q * 128 + (tid & 127);
    const int jh  = tid >> 7;  // 0 or 1

    const float4* __restrict__ x4 = (const float4*)x;
    const float4* __restrict__ y4 = (const float4*)y;
    const int slab = t * 4;  // float4 offset of slab-t within a batch row (row = 512 float4)

    // own row a = x[i, t, :]
    const size_t abase = (size_t)i * (TDIM * CDIM / 4) + slab;
    float4 a0 = x4[abase + 0];
    float4 a1 = x4[abase + 1];
    float4 a2 = x4[abase + 2];
    float4 a3 = x4[abase + 3];
    const float na = norm16(a0, a1, a2, a3);

    float sxx = 0.f, sxy = 0.f;

    for (int c = 0; c < 2; ++c) {
        __syncthreads();  // protect LDS from previous chunk's readers
        // stage row r = c*256 + tid of x and y slabs
        {
            const int r = c * 256 + tid;
            const size_t rb = (size_t)r * (TDIM * CDIM / 4) + slab;
            float4 bx0 = x4[rb + 0], bx1 = x4[rb + 1], bx2 = x4[rb + 2], bx3 = x4[rb + 3];
            float4 by0 = y4[rb + 0], by1 = y4[rb + 1], by2 = y4[rb + 2], by3 = y4[rb + 3];
            sx4[tid * 4 + 0] = bx0; sx4[tid * 4 + 1] = bx1;
            sx4[tid * 4 + 2] = bx2; sx4[tid * 4 + 3] = bx3;
            sy4[tid * 4 + 0] = by0; sy4[tid * 4 + 1] = by1;
            sy4[tid * 4 + 2] = by2; sy4[tid * 4 + 3] = by3;
            snx[tid] = norm16(bx0, bx1, bx2, bx3);
            sny[tid] = norm16(by0, by1, by2, by3);
        }
        __syncthreads();

        const int jb = jh * 128;
        const int jg_base = c * 256;
#pragma unroll 4
        for (int jj = 0; jj < 128; ++jj) {
            const int jl = jb + jj;
            // Kxx contribution (skip diagonal)
            float4 b0 = sx4[jl * 4 + 0], b1 = sx4[jl * 4 + 1];
            float4 b2 = sx4[jl * 4 + 2], b3 = sx4[jl * 4 + 3];
            float dx = dot16(a0, a1, a2, a3, b0, b1, b2, b3);
            float ex = exp2f((dx - 0.5f * (na + snx[jl])) * LOG2E);
            sxx += (i == jg_base + jl) ? 0.f : ex;
            // Kxy contribution
            float4 c0 = sy4[jl * 4 + 0], c1 = sy4[jl * 4 + 1];
            float4 c2 = sy4[jl * 4 + 2], c3 = sy4[jl * 4 + 3];
            float dy = dot16(a0, a1, a2, a3, c0, c1, c2, c3);
            sxy += exp2f((dy - 0.5f * (na + sny[jl])) * LOG2E);
        }
    }

    // block reduction: wave shuffle then LDS
    for (int off = 32; off > 0; off >>= 1) {
        sxx += __shfl_down(sxx, off, 64);
        sxy += __shfl_down(sxy, off, 64);
    }
    const int wid = tid >> 6;
    if ((tid & 63) == 0) { red[wid] = sxx; red[4 + wid] = sxy; }
    __syncthreads();
    if (tid == 0) {
        const float w = (t == 0 || t == TDIM - 1) ? 1.f : 2.f;
        part[bid]       = w * (red[0] + red[1] + red[2] + red[3]);
        part[512 + bid] = w * (red[4] + red[5] + red[6] + red[7]);
    }
}

__global__ __launch_bounds__(256) void finalize_kernel(const float* __restrict__ part,
                                                       float* __restrict__ out) {
    const int tid = threadIdx.x;
    double vxx = (double)part[tid] + (double)part[tid + 256];
    double vxy = (double)part[512 + tid] + (double)part[768 + tid];
    for (int off = 32; off > 0; off >>= 1) {
        vxx += __shfl_down(vxx, off, 64);
        vxy += __shfl_down(vxy, off, 64);
    }
    __shared__ double red[8];
    const int wid = tid >> 6;
    if ((tid & 63) == 0) { red[wid] = vxx; red[4 + wid] = vxy; }
    __syncthreads();
    if (tid == 0) {
        double sxx = red[0] + red[1] + red[2] + red[3];
        double sxy = red[4] + red[5] + red[6] + red[7];
        double e1 = sxx / (254.0 * 512.0 * 511.0);   // off-diagonal mean of Kxx
        double e2 = sxy / (254.0 * 512.0 * 512.0);   // full mean of Kxy
        out[0] = (float)(e1 - 2.0 * e2);
    }
}

extern "C" void kernel_launch(void* const* d_in, const int* in_sizes, int n_in,
                              void* d_out, int out_size, void* d_ws, size_t ws_size,
                              hipStream_t stream) {
    const float* x = (const float*)d_in[0];
    const float* y = (const float*)d_in[1];
    float* out  = (float*)d_out;
    float* part = (float*)d_ws;  // 1024 floats: [0,512) xx partials, [512,1024) xy

    gram_kernel<<<dim3(512), dim3(256), 0, stream>>>(x, y, part);
    finalize_kernel<<<dim3(1), dim3(256), 0, stream>>>(part, out);
}

// Round 2
// 82.735 us; speedup vs baseline: 1.5506x; 1.5506x over previous
//
#include <hip/hip_runtime.h>

// RBF-MMD discriminator: B=512 rows, T=128 slabs, C=16, fp32.
// out = E_xx - 2*E_xy. Per unique slab t (weight 1 for t in {0,127} else 2):
//   Kxx = exp(-(|a|^2+|b|^2-2ab)/2) over X rows, Kxy over X vs Y.
// MFMA path: split-bf16 (hi+lo) GEMM with K packed [hi|lo] into 16x16x32_bf16.
//   S = A1*B1 + A2*B2, A1=[ahi|alo] B1=[bhi|bhi], A2=[ahi|0] B2=[blo|blo]
//     = ahi*bhi + alo*bhi + ahi*blo  (lo*lo dropped, ~2^-18 rel, zero-mean)
// Inputs pre-scaled by sqrt(log2 e) so exp(-d/2) = exp2(dot' - g_a - g_b),
// g = 0.5*log2e*|row|^2 in fp32. Diagonal included, subtracted in finalize.

#define LOG2E 1.4426950408889634f
#define SCALE 1.2011224087864498f   // sqrt(LOG2E)
#define SD 9                        // LDS row stride in dwords: gcd(9,32)=1 -> conflict-free

typedef __attribute__((ext_vector_type(8))) __bf16 bf16x8;
typedef __attribute__((ext_vector_type(4))) float floatx4;

union FragU { unsigned int u[4]; bf16x8 v; };

static __device__ __forceinline__ unsigned short bfbits(__bf16 h) {
    union { __bf16 h; unsigned short s; } u; u.h = h; return u.s;
}
static __device__ __forceinline__ unsigned int packhh(__bf16 a, __bf16 b) {
    return (unsigned int)bfbits(a) | ((unsigned int)bfbits(b) << 16);
}
static __device__ __forceinline__ unsigned int packff(float a, float b) {
    return packhh((__bf16)a, (__bf16)b);
}

// split one float4 (scaled) into hi/lo bf16 pairs, store 2 dwords each
static __device__ __forceinline__ void split_store(unsigned int* H, unsigned int* L,
                                                   int idx, float4 f) {
    float s0 = f.x * SCALE, s1 = f.y * SCALE, s2 = f.z * SCALE, s3 = f.w * SCALE;
    __bf16 h0 = (__bf16)s0, h1 = (__bf16)s1, h2 = (__bf16)s2, h3 = (__bf16)s3;
    H[idx]     = packhh(h0, h1);
    H[idx + 1] = packhh(h2, h3);
    L[idx]     = packff(s0 - (float)h0, s1 - (float)h1);
    L[idx + 1] = packff(s2 - (float)h2, s3 - (float)h3);
}

// grid = 1024: bid>>3 = t, (bid>>1)&3 = A-row strip (128 rows), bid&1 = j-half (256 cols)
// block = 256 threads = 4 waves; wave w owns A rows strip*128 + w*32 (two 16-row tiles).
__global__ __launch_bounds__(256, 4) void gram_kernel(const float* __restrict__ x,
                                                      const float* __restrict__ y,
                                                      float* __restrict__ part) {
    __shared__ unsigned int XH[256 * SD], XL[256 * SD], YH[256 * SD], YL[256 * SD];
    __shared__ float gxs[256], gys[256];
    __shared__ float sgrow[4][2][16];
    __shared__ float red[8];

    const int bid   = blockIdx.x;
    const int t     = bid >> 3;
    const int strip = (bid >> 1) & 3;
    const int jhalf = bid & 1;
    const int tid   = threadIdx.x;
    const int w     = tid >> 6;
    const int lane  = tid & 63;
    const int quad  = lane >> 4;
    const int l15   = lane & 15;
    const int qh    = quad & 1;

    const float4* __restrict__ x4 = (const float4*)x;
    const float4* __restrict__ y4 = (const float4*)y;
    const int slab4 = t * 4;  // float4 offset of slab t within a row (row = 512 float4)

    // ---- stage this block's 256-row j-chunk (split-bf16 + norms) ----
    {
        const int r = tid;
        const size_t gbase = (size_t)(jhalf * 256 + r) * 512 + slab4;
        float gnx = 0.f, gny = 0.f;
#pragma unroll
        for (int d = 0; d < 4; ++d) {
            float4 fx = x4[gbase + d];
            float4 fy = y4[gbase + d];
            gnx += fx.x * fx.x + fx.y * fx.y + fx.z * fx.z + fx.w * fx.w;
            gny += fy.x * fy.x + fy.y * fy.y + fy.z * fy.z + fy.w * fy.w;
            split_store(XH, XL, r * SD + 2 * d, fx);
            split_store(YH, YL, r * SD + 2 * d, fy);
        }
        gxs[r] = 0.5f * LOG2E * gnx;
        gys[r] = 0.5f * LOG2E * gny;
    }

    // ---- per-wave A fragments (from global, split in-register) ----
    bf16x8 a1f[2], a2f[2];
    float preg[2][4];
    const int abase = strip * 128 + w * 32;
    {
        bf16x8 zv;
#pragma unroll
        for (int j = 0; j < 8; ++j) zv[j] = (__bf16)0.0f;
#pragma unroll
        for (int rt = 0; rt < 2; ++rt) {
            const int row = abase + rt * 16 + l15;
            const size_t gb = (size_t)row * 512 + slab4 + qh * 2;
            float4 f0 = x4[gb], f1 = x4[gb + 1];
            float p = f0.x * f0.x + f0.y * f0.y + f0.z * f0.z + f0.w * f0.w
                    + f1.x * f1.x + f1.y * f1.y + f1.z * f1.z + f1.w * f1.w;
            float n = p + __shfl_xor(p, 16, 64);  // combine halves (quad&1 flip)
            if (quad == 0) sgrow[w][rt][l15] = 0.5f * LOG2E * n;
            float sc[8] = { f0.x * SCALE, f0.y * SCALE, f0.z * SCALE, f0.w * SCALE,
                            f1.x * SCALE, f1.y * SCALE, f1.z * SCALE, f1.w * SCALE };
            bf16x8 hv, lv;
#pragma unroll
            for (int j = 0; j < 8; ++j) {
                __bf16 h = (__bf16)sc[j];
                hv[j] = h;
                lv[j] = (__bf16)(sc[j] - (float)h);
            }
            if (quad < 2) { a1f[rt] = hv; a2f[rt] = hv; }
            else          { a1f[rt] = lv; a2f[rt] = zv; }
        }
    }
    __syncthreads();

#pragma unroll
    for (int rt = 0; rt < 2; ++rt)
#pragma unroll
        for (int r = 0; r < 4; ++r)
            preg[rt][r] = -sgrow[w][rt][quad * 4 + r];  // C-row = quad*4+reg (verified layout)

    float sxx[4] = {0.f, 0.f, 0.f, 0.f};
    float sxy[4] = {0.f, 0.f, 0.f, 0.f};

    for (int jt = 0; jt < 16; ++jt) {
        const int jrow = jt * 16 + l15;        // B col n = lane&15
        const int rb = jrow * SD + qh * 4;     // frag dwords: (quad&1)*4 .. +3
        FragU bh, bl, ch, cl;
        bh.u[0] = XH[rb]; bh.u[1] = XH[rb + 1]; bh.u[2] = XH[rb + 2]; bh.u[3] = XH[rb + 3];
        bl.u[0] = XL[rb]; bl.u[1] = XL[rb + 1]; bl.u[2] = XL[rb + 2]; bl.u[3] = XL[rb + 3];
        ch.u[0] = YH[rb]; ch.u[1] = YH[rb + 1]; ch.u[2] = YH[rb + 2]; ch.u[3] = YH[rb + 3];
        cl.u[0] = YL[rb]; cl.u[1] = YL[rb + 1]; cl.u[2] = YL[rb + 2]; cl.u[3] = YL[rb + 3];
        const float gcx = gxs[jrow];
        const float gcy = gys[jrow];
#pragma unroll
        for (int rt = 0; rt < 2; ++rt) {
            floatx4 c = {0.f, 0.f, 0.f, 0.f};
            c = __builtin_amdgcn_mfma_f32_16x16x32_bf16(a1f[rt], bh.v, c, 0, 0, 0);
            c = __builtin_amdgcn_mfma_f32_16x16x32_bf16(a2f[rt], bl.v, c, 0, 0, 0);
#pragma unroll
            for (int r = 0; r < 4; ++r)
                sxx[r] += __builtin_amdgcn_exp2f(c[r] + (preg[rt][r] - gcx));
            floatx4 d = {0.f, 0.f, 0.f, 0.f};
            d = __builtin_amdgcn_mfma_f32_16x16x32_bf16(a1f[rt], ch.v, d, 0, 0, 0);
            d = __builtin_amdgcn_mfma_f32_16x16x32_bf16(a2f[rt], cl.v, d, 0, 0, 0);
#pragma unroll
            for (int r = 0; r < 4; ++r)
                sxy[r] += __builtin_amdgcn_exp2f(d[r] + (preg[rt][r] - gcy));
        }
    }

    // ---- block reduction ----
    float txx = (sxx[0] + sxx[1]) + (sxx[2] + sxx[3]);
    float txy = (sxy[0] + sxy[1]) + (sxy[2] + sxy[3]);
    for (int off = 32; off > 0; off >>= 1) {
        txx += __shfl_down(txx, off, 64);
        txy += __shfl_down(txy, off, 64);
    }
    if (lane == 0) { red[w] = txx; red[4 + w] = txy; }
    __syncthreads();
    if (tid == 0) {
        const float wt = (t == 0 || t == 127) ? 1.f : 2.f;
        part[bid]        = wt * (red[0] + red[1] + red[2] + red[3]);
        part[1024 + bid] = wt * (red[4] + red[5] + red[6] + red[7]);
    }
}

__global__ __launch_bounds__(256) void finalize_kernel(const float* __restrict__ part,
                                                       float* __restrict__ out) {
    const int tid = threadIdx.x;
    double vxx = 0.0, vxy = 0.0;
#pragma unroll
    for (int k = 0; k < 4; ++k) {
        vxx += (double)part[tid + 256 * k];
        vxy += (double)part[1024 + tid + 256 * k];
    }
    for (int off = 32; off > 0; off >>= 1) {
        vxx += __shfl_down(vxx, off, 64);
        vxy += __shfl_down(vxy, off, 64);
    }
    __shared__ double red[8];
    const int wid = tid >> 6;
    if ((tid & 63) == 0) { red[wid] = vxx; red[4 + wid] = vxy; }
    __syncthreads();
    if (tid == 0) {
        double sxx = red[0] + red[1] + red[2] + red[3];
        double sxy = red[4] + red[5] + red[6] + red[7];
        // diagonal entries (computed ~1.0 each) included in sxx: subtract 254*512
        double e1 = (sxx - 254.0 * 512.0) / (254.0 * 512.0 * 511.0);
        double e2 = sxy / (254.0 * 512.0 * 512.0);
        out[0] = (float)(e1 - 2.0 * e2);
    }
}

extern "C" void kernel_launch(void* const* d_in, const int* in_sizes, int n_in,
                              void* d_out, int out_size, void* d_ws, size_t ws_size,
                              hipStream_t stream) {
    (void)in_sizes; (void)n_in; (void)out_size; (void)ws_size;
    const float* x = (const float*)d_in[0];
    const float* y = (const float*)d_in[1];
    float* out  = (float*)d_out;
    float* part = (float*)d_ws;  // 2048 floats: [0,1024) xx, [1024,2048) xy

    gram_kernel<<<dim3(1024), dim3(256), 0, stream>>>(x, y, part);
    finalize_kernel<<<dim3(1), dim3(256), 0, stream>>>(part, out);
}

// Round 3
// 77.512 us; speedup vs baseline: 1.6551x; 1.0674x over previous
//
#include <hip/hip_runtime.h>

// RBF-MMD discriminator: B=512 rows, T=128 slabs, C=16, fp32.
// out = E_xx - 2*E_xy over per-slab RBF grams (slab weight 1 for t in {0,127},
// else 2; 254 weighted slab instances total).
// Split-bf16 MFMA (verified 16x16x32_bf16 layout): S = A1*B1 + A2*B2 with
//   A1=[ahi|alo] B1=[bhi|bhi], A2=[ahi|0] B2=[blo|blo]  (lo*lo dropped).
// Inputs pre-scaled by sqrt(log2 e); entry = exp2(dot') * 2^-gcol * 2^-grow,
// accumulated as fma(exp2(dot'), colscale, acc), row-scaled in epilogue.
// (No exponent cancellation: better numerics than exp2(dot-gr-gc).)

#define LOG2E 1.4426950408889634f
#define SCALE 1.2011224087864498f   // sqrt(LOG2E)

typedef __attribute__((ext_vector_type(8))) __bf16 bf16x8;
typedef __attribute__((ext_vector_type(4))) float floatx4;

union FragU { uint4 q; unsigned int u[4]; bf16x8 v; };

// 16B-aligned group-padded LDS row offset (dwords): 8 dw/row + 4 dw pad per 4 rows.
// Bank pattern over 16 rows x 2 k-halves is uniform (each 4-bank group hit 4x
// per b128 wave read = the b128 minimum -> no extra conflicts).
static __device__ __forceinline__ int off(int n) { return (n << 3) + ((n >> 2) << 2); }

static __device__ __forceinline__ unsigned short bfbits(__bf16 h) {
    union { __bf16 h; unsigned short s; } u; u.h = h; return u.s;
}
static __device__ __forceinline__ unsigned int packhh(__bf16 a, __bf16 b) {
    return (unsigned int)bfbits(a) | ((unsigned int)bfbits(b) << 16);
}

// grid = 1024: bid>>3 = t, (bid>>2)&1 = A-strip (256 rows), bid&3 = j-quarter (128 cols)
// 4 waves; wave w owns A rows strip*256 + w*64 (four 16-row MFMA tiles).
__global__ __launch_bounds__(256, 4) void gram_kernel(const float* __restrict__ x,
                                                      const float* __restrict__ y,
                                                      float* __restrict__ part) {
    __shared__ unsigned int XH[1152], XL[1152], YH[1152], YL[1152];
    __shared__ float csx[128], csy[128];   // 2^-g per j-column
    __shared__ float srg[256];             // g per A-row (local to strip)
    __shared__ float red[8];

    const int bid   = blockIdx.x;
    const int t     = bid >> 3;
    const int strip = (bid >> 2) & 1;
    const int jq    = bid & 3;
    const int tid   = threadIdx.x;
    const int w     = tid >> 6;
    const int lane  = tid & 63;
    const int quad  = lane >> 4;
    const int l15   = lane & 15;
    const int qh    = quad & 1;

    const float4* __restrict__ x4 = (const float4*)x;
    const float4* __restrict__ y4 = (const float4*)y;
    const int slab4 = t * 4;  // float4 offset of slab t within a row (row = 512 float4)

    // ---- stage j-chunk: threads 0..127 -> X rows, 128..255 -> Y rows ----
    {
        const int half = tid >> 7;
        const int n    = tid & 127;
        const float4* __restrict__ src4 = half ? y4 : x4;
        const size_t gb = (size_t)(jq * 128 + n) * 512 + slab4;
        float4 f0 = src4[gb], f1 = src4[gb + 1], f2 = src4[gb + 2], f3 = src4[gb + 3];
        float fs[16] = { f0.x, f0.y, f0.z, f0.w, f1.x, f1.y, f1.z, f1.w,
                         f2.x, f2.y, f2.z, f2.w, f3.x, f3.y, f3.z, f3.w };
        float g = 0.f;
        unsigned int hw[8], lw[8];
#pragma unroll
        for (int p = 0; p < 8; ++p) {
            float s0 = fs[2 * p] * SCALE, s1 = fs[2 * p + 1] * SCALE;
            g += fs[2 * p] * fs[2 * p] + fs[2 * p + 1] * fs[2 * p + 1];
            __bf16 h0 = (__bf16)s0, h1 = (__bf16)s1;
            hw[p] = packhh(h0, h1);
            lw[p] = packhh((__bf16)(s0 - (float)h0), (__bf16)(s1 - (float)h1));
        }
        unsigned int* __restrict__ H = half ? YH : XH;
        unsigned int* __restrict__ L = half ? YL : XL;
        const int o = off(n);
        *(uint4*)&H[o]     = make_uint4(hw[0], hw[1], hw[2], hw[3]);
        *(uint4*)&H[o + 4] = make_uint4(hw[4], hw[5], hw[6], hw[7]);
        *(uint4*)&L[o]     = make_uint4(lw[0], lw[1], lw[2], lw[3]);
        *(uint4*)&L[o + 4] = make_uint4(lw[4], lw[5], lw[6], lw[7]);
        float* cs = half ? csy : csx;
        cs[n] = __builtin_amdgcn_exp2f(-0.5f * LOG2E * g);
    }
    // ---- A-row norms for this strip (rowscale applied in epilogue) ----
    {
        const size_t gb = (size_t)(strip * 256 + tid) * 512 + slab4;
        float4 f0 = x4[gb], f1 = x4[gb + 1], f2 = x4[gb + 2], f3 = x4[gb + 3];
        float g = f0.x * f0.x + f0.y * f0.y + f0.z * f0.z + f0.w * f0.w
                + f1.x * f1.x + f1.y * f1.y + f1.z * f1.z + f1.w * f1.w
                + f2.x * f2.x + f2.y * f2.y + f2.z * f2.z + f2.w * f2.w
                + f3.x * f3.x + f3.y * f3.y + f3.z * f3.z + f3.w * f3.w;
        srg[tid] = 0.5f * LOG2E * g;
    }

    // ---- per-wave A fragments: 4 row-tiles, split-bf16 in-register ----
    bf16x8 a1f[4], a2f[4];
    {
        bf16x8 zv;
#pragma unroll
        for (int j = 0; j < 8; ++j) zv[j] = (__bf16)0.0f;
#pragma unroll
        for (int rt = 0; rt < 4; ++rt) {
            const int row = strip * 256 + w * 64 + rt * 16 + l15;
            const size_t gb = (size_t)row * 512 + slab4 + qh * 2;
            float4 f0 = x4[gb], f1 = x4[gb + 1];
            float sc[8] = { f0.x * SCALE, f0.y * SCALE, f0.z * SCALE, f0.w * SCALE,
                            f1.x * SCALE, f1.y * SCALE, f1.z * SCALE, f1.w * SCALE };
            bf16x8 hv, lv;
#pragma unroll
            for (int j = 0; j < 8; ++j) {
                __bf16 h = (__bf16)sc[j];
                hv[j] = h;
                lv[j] = (__bf16)(sc[j] - (float)h);
            }
            a1f[rt] = (quad < 2) ? hv : lv;   // A1 = [ahi | alo]
            a2f[rt] = (quad < 2) ? hv : zv;   // A2 = [ahi |  0 ]
        }
    }
    __syncthreads();

    float sxx[4][4], sxy[4][4];
#pragma unroll
    for (int rt = 0; rt < 4; ++rt)
#pragma unroll
        for (int r = 0; r < 4; ++r) { sxx[rt][r] = 0.f; sxy[rt][r] = 0.f; }

    // ---- main loop: 8 j-tiles of 16 columns ----
    for (int jt = 0; jt < 8; ++jt) {
        const int n  = jt * 16 + l15;       // C col = lane&15 (verified layout)
        const int rb = off(n) + qh * 4;     // frag dwords, 16B aligned
        FragU bh, bl, ch, cl;
        bh.q = *(const uint4*)&XH[rb];
        bl.q = *(const uint4*)&XL[rb];
        ch.q = *(const uint4*)&YH[rb];
        cl.q = *(const uint4*)&YL[rb];
        const float cx = csx[n];
        const float cy = csy[n];
#pragma unroll
        for (int rt = 0; rt < 4; ++rt) {
            floatx4 c = {0.f, 0.f, 0.f, 0.f};
            c = __builtin_amdgcn_mfma_f32_16x16x32_bf16(a1f[rt], bh.v, c, 0, 0, 0);
            c = __builtin_amdgcn_mfma_f32_16x16x32_bf16(a2f[rt], bl.v, c, 0, 0, 0);
#pragma unroll
            for (int r = 0; r < 4; ++r)
                sxx[rt][r] = fmaf(__builtin_amdgcn_exp2f(c[r]), cx, sxx[rt][r]);
            floatx4 d = {0.f, 0.f, 0.f, 0.f};
            d = __builtin_amdgcn_mfma_f32_16x16x32_bf16(a1f[rt], ch.v, d, 0, 0, 0);
            d = __builtin_amdgcn_mfma_f32_16x16x32_bf16(a2f[rt], cl.v, d, 0, 0, 0);
#pragma unroll
            for (int r = 0; r < 4; ++r)
                sxy[rt][r] = fmaf(__builtin_amdgcn_exp2f(d[r]), cy, sxy[rt][r]);
        }
    }

    // ---- epilogue: row-scale by 2^-g_row, then block reduction ----
    float txx = 0.f, txy = 0.f;
#pragma unroll
    for (int rt = 0; rt < 4; ++rt)
#pragma unroll
        for (int r = 0; r < 4; ++r) {
            const float rs = __builtin_amdgcn_exp2f(-srg[w * 64 + rt * 16 + quad * 4 + r]);
            txx = fmaf(sxx[rt][r], rs, txx);
            txy = fmaf(sxy[rt][r], rs, txy);
        }
    for (int o = 32; o > 0; o >>= 1) {
        txx += __shfl_down(txx, o, 64);
        txy += __shfl_down(txy, o, 64);
    }
    if (lane == 0) { red[w] = txx; red[4 + w] = txy; }
    __syncthreads();
    if (tid == 0) {
        const float wt = (t == 0 || t == 127) ? 1.f : 2.f;
        part[bid]        = wt * (red[0] + red[1] + red[2] + red[3]);
        part[1024 + bid] = wt * (red[4] + red[5] + red[6] + red[7]);
    }
}

__global__ __launch_bounds__(256) void finalize_kernel(const float* __restrict__ part,
                                                       float* __restrict__ out) {
    const int tid = threadIdx.x;
    double vxx = 0.0, vxy = 0.0;
#pragma unroll
    for (int k = 0; k < 4; ++k) {
        vxx += (double)part[tid + 256 * k];
        vxy += (double)part[1024 + tid + 256 * k];
    }
    for (int o = 32; o > 0; o >>= 1) {
        vxx += __shfl_down(vxx, o, 64);
        vxy += __shfl_down(vxy, o, 64);
    }
    __shared__ double red[8];
    const int wid = tid >> 6;
    if ((tid & 63) == 0) { red[wid] = vxx; red[4 + wid] = vxy; }
    __syncthreads();
    if (tid == 0) {
        double sxx = red[0] + red[1] + red[2] + red[3];
        double sxy = red[4] + red[5] + red[6] + red[7];
        // diagonal entries (~1.0 each) included in sxx: subtract 254*512
        double e1 = (sxx - 254.0 * 512.0) / (254.0 * 512.0 * 511.0);
        double e2 = sxy / (254.0 * 512.0 * 512.0);
        out[0] = (float)(e1 - 2.0 * e2);
    }
}

extern "C" void kernel_launch(void* const* d_in, const int* in_sizes, int n_in,
                              void* d_out, int out_size, void* d_ws, size_t ws_size,
                              hipStream_t stream) {
    (void)in_sizes; (void)n_in; (void)out_size; (void)ws_size;
    const float* x = (const float*)d_in[0];
    const float* y = (const float*)d_in[1];
    float* out  = (float*)d_out;
    float* part = (float*)d_ws;  // 2048 floats: [0,1024) xx, [1024,2048) xy

    gram_kernel<<<dim3(1024), dim3(256), 0, stream>>>(x, y, part);
    finalize_kernel<<<dim3(1), dim3(256), 0, stream>>>(part, out);
}